// Round 9
// baseline (216.092 us; speedup 1.0000x reference)
//
#include <hip/hip_runtime.h>
#include <stdint.h>

// GateDotProductAttention: B=8,S=2048,D=256 fp32 in/out.
// prep: K,V -> bf16 images in exact 32x32x16-MFMA fragment order; W -> bf16 swizzled chunks.
// attn: bidirectional flash, no-max softmax, 32x32x16 MFMAs, waves=(qh,jh,dh) with QK dup
//       across dh pair; P repacked in-register (pk2 + permlane32_swap); V B-frags direct
//       from L2 (chunked loads); K staged via linear global_load_lds; fused gate epilogue.
// R9 = R8 with __launch_bounds__(512) (256-VGPR cap, was 128 -> catastrophic spill) and
//      reduced transient register pressure (chunked V, inline diag masks).

typedef unsigned short u16;
typedef unsigned int u32;
typedef __attribute__((ext_vector_type(8))) short short8;
typedef __attribute__((ext_vector_type(4))) float f32x4;
typedef __attribute__((ext_vector_type(16))) float f32x16;

#define B_ 8
#define S_ 2048
#define D_ 256
#define NP 32            // periods of 64 j-rows

#define LOG2E 1.44269504088896340736f
#define QSCALE (LOG2E/16.0f)

#define KIMG_OFF 0u          // 8MB: [b][jb 0..63] 16KB tiles, frag order (ks*64+lane)*16
#define VIMG_OFF (8u<<20)    // 8MB: [b][jb] 16KB tiles, frag order ((db*2+ks2)*64+lane)*16
#define WBF_OFF  (16u<<20)   // 512KB: (db*4+m) 8KB swizzled slices

__device__ __forceinline__ u16 f2bf(float f) {
    union { float f; u32 u; } x; x.f = f;
    u32 u = x.u + 0x7fffu + ((x.u >> 16) & 1u);   // RNE
    return (u16)(u >> 16);
}
__device__ __forceinline__ short8 pack8(float4 a, float4 b) {
    short8 r;
    r[0] = (short)f2bf(a.x); r[1] = (short)f2bf(a.y);
    r[2] = (short)f2bf(a.z); r[3] = (short)f2bf(a.w);
    r[4] = (short)f2bf(b.x); r[5] = (short)f2bf(b.y);
    r[6] = (short)f2bf(b.z); r[7] = (short)f2bf(b.w);
    return r;
}
__device__ __forceinline__ f32x4 mfma16(short8 a, short8 b, f32x4 c) {
    return __builtin_amdgcn_mfma_f32_16x16x32_bf16(a, b, c, 0, 0, 0);
}
__device__ __forceinline__ f32x16 mfma32(short8 a, short8 b, f32x16 c) {
    return __builtin_amdgcn_mfma_f32_32x32x16_bf16(a, b, c, 0, 0, 0);
}
__device__ __forceinline__ u32 pk2(float a, float b) {
    u32 w;
    asm("v_cvt_pk_bf16_f32 %0, %1, %2" : "=v"(w) : "v"(a), "v"(b));
    return w;
}
// v_permlane32_swap_b32: a[32+i] <- b_old[i]; b[i] <- a_old[32+i]
__device__ __forceinline__ void plswap(u32& a, u32& b) {
    asm volatile("v_permlane32_swap_b32 %0, %1" : "+v"(a), "+v"(b));
}
__device__ __forceinline__ void gload_lds(const void* g, void* lds) {
    __builtin_amdgcn_global_load_lds(
        (const __attribute__((address_space(1))) void*)g,
        (__attribute__((address_space(3))) void*)lds, 16, 0, 0);
}

// ---------------------------------------------------------------- prep ----
__global__ __launch_bounds__(256, 1)
void prep_kernel(const float* __restrict__ k, const float* __restrict__ v,
                 const float* __restrict__ w0, const float* __restrict__ w1,
                 const float* __restrict__ w2, const float* __restrict__ w3,
                 char* __restrict__ ws)
{
    const int tid = (int)threadIdx.x;
    const int bid = (int)blockIdx.x;

    if (bid < 1024) {
        // K or V fragment-order tile for (b, jb): stage 32x256 f32 in LDS, gather-emit.
        __shared__ float st[32][264];
        const bool isV = (bid < 512);
        const int t = isV ? bid : bid - 512;
        const int b = t >> 6, jb = t & 63;
        const float* src = (isV ? v : k) + ((size_t)b * S_ + (size_t)jb * 32) * D_;
        const int jr = tid >> 3, d0 = (tid & 7) * 32;
        #pragma unroll
        for (int i = 0; i < 8; ++i) {
            float4 x = *(const float4*)(src + (size_t)jr * D_ + d0 + i * 4);
            *(float4*)&st[jr][d0 + i * 4] = x;
        }
        __syncthreads();
        char* ob = ws + (isV ? VIMG_OFF : KIMG_OFF)
                 + ((size_t)b * 64 + jb) * 16384;
        #pragma unroll
        for (int it = 0; it < 4; ++it) {
            int e = it * 256 + tid;           // entry 0..1023
            int fi = e >> 6, l = e & 63;
            short8 o;
            if (isV) {
                // V B-frag: V[ks2*16+8*(l>>5)+i][db*32+(l&31)]
                int db = fi >> 1, ks2 = fi & 1;
                int row = ks2 * 16 + (l >> 5) * 8, col = db * 32 + (l & 31);
                #pragma unroll
                for (int i = 0; i < 8; ++i) o[i] = (short)f2bf(st[row + i][col]);
            } else {
                // K A-frag: K[(l&31)][ks*16+8*(l>>5)+i]
                int ks = fi;
                int row = l & 31, col = ks * 16 + (l >> 5) * 8;
                #pragma unroll
                for (int i = 0; i < 8; ++i) o[i] = (short)f2bf(st[row][col + i]);
            }
            *(short8*)(ob + e * 16) = o;
        }
    } else {
        // W slice (m, db): 16 rows x 256 cols -> swizzled bf16, chunk order (db*4+m)
        const int t = bid - 1024, m = t >> 4, db = t & 15;
        const float* wsrc = (m == 0 ? w0 : m == 1 ? w1 : m == 2 ? w2 : w3)
                            + (size_t)(db * 16) * D_;
        char* ob = ws + WBF_OFF + (size_t)(db * 4 + m) * 8192;
        #pragma unroll
        for (int it = 0; it < 2; ++it) {
            int gi = tid + it * 256;
            int r = gi >> 5, cg = gi & 31;
            float4 x0 = *(const float4*)(wsrc + (size_t)r * D_ + cg * 8);
            float4 x1 = *(const float4*)(wsrc + (size_t)r * D_ + cg * 8 + 4);
            *(short8*)(ob + r * 512 + ((cg * 16) ^ ((r & 7) << 4))) = pack8(x0, x1);
        }
    }
}

// ---------------------------------------------------------------- attn ----
union PaU { u32 w[4]; short8 s; };

__global__ __launch_bounds__(512)
void attn_kernel(const float* __restrict__ q, const char* __restrict__ kimg,
                 const char* __restrict__ vimg, const char* __restrict__ wbf,
                 const float* __restrict__ v,
                 const float* __restrict__ bo0, const float* __restrict__ bo1,
                 float* __restrict__ out)
{
    __shared__ char smem[133632];

    const int tid = (int)threadIdx.x;
    const int wv = tid >> 6, lane = tid & 63;
    const int qh = wv & 1, jh = (wv >> 1) & 1, dh = wv >> 2;
    const int h = lane >> 5, ln = lane & 31;
    const int g = (lane & 63) >> 4, c = lane & 15;   // gate-phase decomposition
    const int bid = (int)blockIdx.x;
    const int b = bid & 7, qi = bid >> 3;
    const int q0 = qi * 64;
    const int qb = qi * 2 + qh;            // this wave's 32-row q block index
    const int qg = q0 + qh * 32 + ln;      // lane's q (lane axis of C)

    const char* kbaseg = kimg + ((size_t)b << 20);
    const char* vbaseg = vimg + ((size_t)b << 20);

    // Q B-frags, pre-scaled: B[k][n=q]: lane ln = q col, k-chunk = 8h
    short8 qf[16];
    {
        const float* qp = q + ((size_t)b * S_ + (size_t)(q0 + qh * 32 + ln)) * D_ + h * 8;
        #pragma unroll
        for (int ks = 0; ks < 16; ++ks) {
            float4 a = *(const float4*)(qp + ks * 16);
            float4 d = *(const float4*)(qp + ks * 16 + 4);
            a.x *= QSCALE; a.y *= QSCALE; a.z *= QSCALE; a.w *= QSCALE;
            d.x *= QSCALE; d.y *= QSCALE; d.z *= QSCALE; d.w *= QSCALE;
            qf[ks] = pack8(a, d);
        }
    }

    f32x16 accF[4] = {}, accB[4] = {};
    float sF = 0.0f, sB = 0.0f;

    #define STAGE_K(t, buf)                                                    \
        {                                                                      \
            const char* kg_ = kbaseg + (size_t)(t) * 32768;                    \
            _Pragma("unroll")                                                  \
            for (int i = 0; i < 4; ++i) {                                      \
                int off = i * 8192 + wv * 1024;                                \
                gload_lds(kg_ + off + lane * 16, smem + (buf) * 32768 + off);  \
            }                                                                  \
        }

    STAGE_K(0, 0);
    __syncthreads();

    // PV with chunked V loads (<=2 frags live) to cap register pressure
    #define PVALL(pa0_, pa1_, acc_, vg_)                                       \
        {                                                                      \
            short8 va_ = *(const short8*)(vg_);                                \
            short8 vb_ = *(const short8*)((vg_) + 1024);                       \
            __builtin_amdgcn_s_setprio(1);                                     \
            acc_[0] = mfma32(pa0_, va_, acc_[0]);                              \
            va_ = *(const short8*)((vg_) + 2048);                              \
            acc_[0] = mfma32(pa1_, vb_, acc_[0]);                              \
            vb_ = *(const short8*)((vg_) + 3072);                              \
            acc_[1] = mfma32(pa0_, va_, acc_[1]);                              \
            va_ = *(const short8*)((vg_) + 4096);                              \
            acc_[1] = mfma32(pa1_, vb_, acc_[1]);                              \
            vb_ = *(const short8*)((vg_) + 5120);                              \
            acc_[2] = mfma32(pa0_, va_, acc_[2]);                              \
            va_ = *(const short8*)((vg_) + 6144);                              \
            acc_[2] = mfma32(pa1_, vb_, acc_[2]);                              \
            vb_ = *(const short8*)((vg_) + 7168);                              \
            acc_[3] = mfma32(pa0_, va_, acc_[3]);                              \
            acc_[3] = mfma32(pa1_, vb_, acc_[3]);                              \
            __builtin_amdgcn_s_setprio(0);                                     \
        }

    // repack 8 dwords (pk2'd bf16 pairs) -> two PV A-frags
    #define REPACK8(pa0_, pa1_, w0_, w1_, w2_, w3_, w4_, w5_, w6_, w7_)        \
        {                                                                      \
            plswap(w0_, w2_); plswap(w1_, w3_);                                \
            plswap(w4_, w6_); plswap(w5_, w7_);                                \
            PaU u0_; u0_.w[0] = w0_; u0_.w[1] = w1_; u0_.w[2] = w2_; u0_.w[3] = w3_; \
            PaU u1_; u1_.w[0] = w4_; u1_.w[1] = w5_; u1_.w[2] = w6_; u1_.w[3] = w7_; \
            pa0_ = u0_.s; pa1_ = u1_.s;                                        \
        }

    // masked exp'd score for reg r on the diagonal tile (j offset = (r&3)+8*(r>>2)+4h)
    #define ME(r_, CMP) (((jbh + ((r_ & 3) + 8 * (r_ >> 2))) CMP qg) ? sc[r_] : 0.0f)

    #pragma unroll 1
    for (int t = 0; t < NP; ++t) {
        const int cur = t & 1;
        if (t + 1 < NP) STAGE_K(t + 1, cur ^ 1);

        const int jbg = 2 * t + jh;
        const char* vg = vbaseg + (size_t)jbg * 16384 + dh * 8192 + lane * 16;

        // QK^T swapped: C[m=j][n=q], A = K frags (LDS, frag-linear), B = Q regs
        const char* kc_ = smem + cur * 32768 + jh * 16384 + lane * 16;
        f32x16 sc = {};
        __builtin_amdgcn_s_setprio(1);
        #pragma unroll
        for (int ks = 0; ks < 16; ++ks) {
            short8 kb = *(const short8*)(kc_ + ks * 1024);
            sc = mfma32(kb, qf[ks], sc);
        }
        __builtin_amdgcn_s_setprio(0);

        #pragma unroll
        for (int i = 0; i < 16; ++i) sc[i] = exp2f(sc[i]);

        if (jbg != qb) {
            u32 w0 = pk2(sc[0], sc[1]),   w1 = pk2(sc[2], sc[3]);
            u32 w2 = pk2(sc[4], sc[5]),   w3 = pk2(sc[6], sc[7]);
            u32 w4 = pk2(sc[8], sc[9]),   w5 = pk2(sc[10], sc[11]);
            u32 w6 = pk2(sc[12], sc[13]), w7 = pk2(sc[14], sc[15]);
            short8 pa0, pa1;
            REPACK8(pa0, pa1, w0, w1, w2, w3, w4, w5, w6, w7);
            float ts = (((sc[0]+sc[1])+(sc[2]+sc[3]))+((sc[4]+sc[5])+(sc[6]+sc[7])))
                     + (((sc[8]+sc[9])+(sc[10]+sc[11]))+((sc[12]+sc[13])+(sc[14]+sc[15])));
            if (jbg < qb) { sB += ts; PVALL(pa0, pa1, accB, vg); }
            else          { sF += ts; PVALL(pa0, pa1, accF, vg); }
        } else {
            const int jbh = jbg * 32 + 4 * h;
            {   // bw: j <= q
                u32 w0 = pk2(ME(0,<=), ME(1,<=)),   w1 = pk2(ME(2,<=), ME(3,<=));
                u32 w2 = pk2(ME(4,<=), ME(5,<=)),   w3 = pk2(ME(6,<=), ME(7,<=));
                u32 w4 = pk2(ME(8,<=), ME(9,<=)),   w5 = pk2(ME(10,<=), ME(11,<=));
                u32 w6 = pk2(ME(12,<=), ME(13,<=)), w7 = pk2(ME(14,<=), ME(15,<=));
                float ts = 0.0f;
                #pragma unroll
                for (int r = 0; r < 16; ++r) ts += ME(r, <=);
                short8 pa0, pa1;
                REPACK8(pa0, pa1, w0, w1, w2, w3, w4, w5, w6, w7);
                sB += ts;
                PVALL(pa0, pa1, accB, vg);
            }
            {   // fw: j >= q
                u32 w0 = pk2(ME(0,>=), ME(1,>=)),   w1 = pk2(ME(2,>=), ME(3,>=));
                u32 w2 = pk2(ME(4,>=), ME(5,>=)),   w3 = pk2(ME(6,>=), ME(7,>=));
                u32 w4 = pk2(ME(8,>=), ME(9,>=)),   w5 = pk2(ME(10,>=), ME(11,>=));
                u32 w6 = pk2(ME(12,>=), ME(13,>=)), w7 = pk2(ME(14,>=), ME(15,>=));
                float ts = 0.0f;
                #pragma unroll
                for (int r = 0; r < 16; ++r) ts += ME(r, >=);
                short8 pa0, pa1;
                REPACK8(pa0, pa1, w0, w1, w2, w3, w4, w5, w6, w7);
                sF += ts;
                PVALL(pa0, pa1, accF, vg);
            }
        }
        __syncthreads();
    }

    // ---- epilogue ----
    // P0: jh=1 writes accF partial -> F region; jh=0 writes accB -> B region.
    {
        float* dst = (float*)(smem + (jh ? 0 : 65536)) + (qh * 2 + dh) * 4096;
        #pragma unroll
        for (int db = 0; db < 4; ++db)
            #pragma unroll
            for (int r = 0; r < 16; ++r)
                dst[(db * 16 + r) * 64 + lane] = jh ? accF[db][r] : accB[db][r];
        if (dh == 0) {
            ((float*)(smem + 131072))[(qh * 2 + jh) * 64 + lane] = sF;
            ((float*)(smem + 132096))[(qh * 2 + jh) * 64 + lane] = sB;
        }
    }
    __syncthreads();

    // P1: merge partner's partial; one wave per qh computes reciprocal sums.
    {
        const float* src = (const float*)(smem + (jh ? 65536 : 0)) + (qh * 2 + dh) * 4096;
        #pragma unroll
        for (int db = 0; db < 4; ++db)
            #pragma unroll
            for (int r = 0; r < 16; ++r) {
                float p = src[(db * 16 + r) * 64 + lane];
                if (jh) accB[db][r] += p; else accF[db][r] += p;
            }
        if (jh == 0 && dh == 0) {
            const float* pf = (const float*)(smem + (h ? 132096 : 131072));
            int qq = ln;
            float s = pf[(qh * 2 + 0) * 64 + qq] + pf[(qh * 2 + 0) * 64 + 32 + qq]
                    + pf[(qh * 2 + 1) * 64 + qq] + pf[(qh * 2 + 1) * 64 + 32 + qq];
            ((float*)(smem + 133120))[h * 64 + qh * 32 + qq] = 1.0f / s;
        }
    }
    __syncthreads();

    // P2: normalize + write att image (jh=0 -> F @[0,32K), jh=1 -> B @[32K,64K)); stage W chunk 0
    {
        const float* rsp = (const float*)(smem + 133120) + jh * 64;
        char* imgb = smem + jh * 32768;
        #pragma unroll
        for (int db = 0; db < 4; ++db)
            #pragma unroll
            for (int r = 0; r < 16; ++r) {
                int qib = (r & 3) + 8 * (r >> 2) + 4 * h;       // q within 32-block
                float m = (jh ? accB[db][r] : accF[db][r]) * rsp[qh * 32 + qib];
                int row = qh * 32 + qib;
                int dcol = dh * 128 + db * 32 + ln;
                *(u16*)(imgb + row * 512 + ((2 * dcol) ^ ((row & 7) << 4))) = f2bf(m);
            }
    }
    #define WSTAGE(db, buf)                                                    \
        {                                                                      \
            const char* gsrc = wbf + (size_t)(db) * 32768;                     \
            _Pragma("unroll")                                                  \
            for (int i = 0; i < 4; ++i) {                                      \
                int off = i * 8192 + wv * 1024;                                \
                gload_lds(gsrc + off + lane * 16,                              \
                          smem + 65536 + (buf) * 32768 + off);                 \
            }                                                                  \
        }
    WSTAGE(0, 0);
    __syncthreads();

    // P3: gate phase. roles: dir = jh, row group wl2 = qh*2+dh (16 rows each).
    const int wl2 = qh * 2 + dh;
    const int swz = (c & 7) << 4;
    short8 af[8], vf[8];
    {
        const char* imgb = smem + jh * 32768;
        int lr = wl2 * 16 + c;
        #pragma unroll
        for (int ks = 0; ks < 8; ++ks) {
            int inner = (ks * 64 + g * 16) ^ ((lr & 7) << 4);
            af[ks] = *(const short8*)(imgb + lr * 512 + inner);
        }
        const float* vp = v + ((size_t)b * S_ + (size_t)(q0 + wl2 * 16 + c)) * D_;
        #pragma unroll
        for (int ks = 0; ks < 8; ++ks) {
            float4 a = *(const float4*)(vp + ks * 32 + g * 8);
            float4 d = *(const float4*)(vp + ks * 32 + g * 8 + 4);
            vf[ks] = pack8(a, d);
        }
    }

    const float* bias = jh ? bo1 : bo0;
    const float* vrow = v + ((size_t)b * S_ + (size_t)(q0 + wl2 * 16)) * D_;
    const char* imgb2 = smem + jh * 32768;
    float* ob = out + ((size_t)b * S_ + (size_t)(q0 + wl2 * 16)) * 512 + jh * 256;
    #pragma unroll
    for (int db = 0; db < 16; ++db) {
        const int cu2 = db & 1;
        if (db + 1 < 16) WSTAGE(db + 1, cu2 ^ 1);

        float bb = bias[db * 16 + c];
        f32x4 a = {bb, bb, bb, bb};
        const char* wc = smem + 65536 + cu2 * 32768 + jh * 16384;
        __builtin_amdgcn_s_setprio(1);
        #pragma unroll
        for (int ks = 0; ks < 8; ++ks) {
            int inner = (ks * 64 + g * 16) ^ swz;
            short8 wi = *(const short8*)(wc + c * 512 + inner);
            short8 wo = *(const short8*)(wc + 8192 + c * 512 + inner);
            a = mfma16(vf[ks], wi, a);
            a = mfma16(af[ks], wo, a);
        }
        __builtin_amdgcn_s_setprio(0);

        #pragma unroll
        for (int r = 0; r < 4; ++r) {
            int row = wl2 * 16 + g * 4 + r;
            int cc = db * 16 + c;
            float vv = vrow[(size_t)(g * 4 + r) * D_ + cc];
            u32 mu = *(const u16*)(imgb2 + row * 512 + ((2 * cc) ^ ((row & 7) << 4)));
            union { u32 u; float f; } cv; cv.u = mu << 16;
            float gate = 1.0f / (1.0f + exp2f(-a[r] * LOG2E));
            ob[(size_t)(g * 4 + r) * 512 + cc] = gate * cv.f + (1.0f - gate) * vv;
        }
        __syncthreads();
    }
}

extern "C" void kernel_launch(void* const* d_in, const int* in_sizes, int n_in,
                              void* d_out, int out_size, void* d_ws, size_t ws_size,
                              hipStream_t stream)
{
    const float* q   = (const float*)d_in[0];
    const float* k   = (const float*)d_in[1];
    const float* v   = (const float*)d_in[2];
    const float* Wi0 = (const float*)d_in[3];
    const float* Wi1 = (const float*)d_in[4];
    const float* Wo0 = (const float*)d_in[5];
    const float* Wo1 = (const float*)d_in[6];
    const float* bo0 = (const float*)d_in[7];
    const float* bo1 = (const float*)d_in[8];
    float* out = (float*)d_out;
    char* ws = (char*)d_ws;
    (void)in_sizes; (void)n_in; (void)ws_size; (void)out_size;

    prep_kernel<<<dim3(1088), dim3(256), 0, stream>>>(k, v, Wi0, Wo0, Wi1, Wo1, ws);
    attn_kernel<<<dim3(256), dim3(512), 0, stream>>>(q, ws + KIMG_OFF, ws + VIMG_OFF,
                                                     ws + WBF_OFF, v, bo0, bo1, out);
}

// Round 10
// 149.189 us; speedup vs baseline: 1.4484x; 1.4484x over previous
//
#include <hip/hip_runtime.h>
#include <stdint.h>

// GateDotProductAttention: B=8,S=2048,D=256 fp32 in/out.
// prep: K,V -> bf16 images in exact 32x32x16-MFMA fragment order; W -> bf16 swizzled chunks.
// attn R10: waves = (qh x2, dh x4). QK k-split 4-way (qf[4]) + LDS partial exchange
//   (raw s_barrier, lgkm-only wait); PV d-split 4-way (acc 64 f32); every wave sees every
//   j-block -> no merge epilogue. P repack in-register (pk2 + permlane32_swap, verified R8).
//   K/V staged from frag-linear images via global_load_lds; fused gate GEMM epilogue.

typedef unsigned short u16;
typedef unsigned int u32;
typedef __attribute__((ext_vector_type(8))) short short8;
typedef __attribute__((ext_vector_type(4))) float f32x4;
typedef __attribute__((ext_vector_type(16))) float f32x16;

#define B_ 8
#define S_ 2048
#define D_ 256
#define NP2 64           // periods of 32 j-rows

#define LOG2E 1.44269504088896340736f
#define QSCALE (LOG2E/16.0f)

#define KIMG_OFF 0u          // 8MB: [b][jb 0..63] 16KB tiles, frag ks*1024 + lane*16
#define VIMG_OFF (8u<<20)    // 8MB: [b][jb] 16KB tiles, frag (db*2+ks2)*1024 + lane*16
#define WBF_OFF  (16u<<20)   // 512KB: (db*4+m) 8KB swizzled slices

// LDS map (main loop): K dbuf [0,32K) ; V dbuf [32K,64K) ; exch [64K,64K+40K)
// epilogue: att image F@[0,32K) B@[32K,64K); W dbuf @64K+buf*32K; recips @131072
#define EXCH 65536
#define SUMS 131072

__device__ __forceinline__ u16 f2bf(float f) {
    union { float f; u32 u; } x; x.f = f;
    u32 u = x.u + 0x7fffu + ((x.u >> 16) & 1u);   // RNE
    return (u16)(u >> 16);
}
__device__ __forceinline__ short8 pack8(float4 a, float4 b) {
    short8 r;
    r[0] = (short)f2bf(a.x); r[1] = (short)f2bf(a.y);
    r[2] = (short)f2bf(a.z); r[3] = (short)f2bf(a.w);
    r[4] = (short)f2bf(b.x); r[5] = (short)f2bf(b.y);
    r[6] = (short)f2bf(b.z); r[7] = (short)f2bf(b.w);
    return r;
}
__device__ __forceinline__ f32x4 mfma16(short8 a, short8 b, f32x4 c) {
    return __builtin_amdgcn_mfma_f32_16x16x32_bf16(a, b, c, 0, 0, 0);
}
__device__ __forceinline__ f32x16 mfma32(short8 a, short8 b, f32x16 c) {
    return __builtin_amdgcn_mfma_f32_32x32x16_bf16(a, b, c, 0, 0, 0);
}
__device__ __forceinline__ u32 pk2(float a, float b) {
    u32 w;
    asm("v_cvt_pk_bf16_f32 %0, %1, %2" : "=v"(w) : "v"(a), "v"(b));
    return w;
}
// v_permlane32_swap_b32: a[32+i] <- b_old[i]; b[i] <- a_old[32+i]
__device__ __forceinline__ void plswap(u32& a, u32& b) {
    asm volatile("v_permlane32_swap_b32 %0, %1" : "+v"(a), "+v"(b));
}
__device__ __forceinline__ void gload_lds(const void* g, void* lds) {
    __builtin_amdgcn_global_load_lds(
        (const __attribute__((address_space(1))) void*)g,
        (__attribute__((address_space(3))) void*)lds, 16, 0, 0);
}

// ---------------------------------------------------------------- prep ----
__global__ __launch_bounds__(256, 1)
void prep_kernel(const float* __restrict__ k, const float* __restrict__ v,
                 const float* __restrict__ w0, const float* __restrict__ w1,
                 const float* __restrict__ w2, const float* __restrict__ w3,
                 char* __restrict__ ws)
{
    const int tid = (int)threadIdx.x;
    const int bid = (int)blockIdx.x;

    if (bid < 1024) {
        // K or V fragment-order tile for (b, jb): stage 32x256 f32 in LDS, gather-emit.
        __shared__ float st[32][264];
        const bool isV = (bid < 512);
        const int t = isV ? bid : bid - 512;
        const int b = t >> 6, jb = t & 63;
        const float* src = (isV ? v : k) + ((size_t)b * S_ + (size_t)jb * 32) * D_;
        const int jr = tid >> 3, d0 = (tid & 7) * 32;
        #pragma unroll
        for (int i = 0; i < 8; ++i) {
            float4 x = *(const float4*)(src + (size_t)jr * D_ + d0 + i * 4);
            *(float4*)&st[jr][d0 + i * 4] = x;
        }
        __syncthreads();
        char* ob = ws + (isV ? VIMG_OFF : KIMG_OFF)
                 + ((size_t)b * 64 + jb) * 16384;
        #pragma unroll
        for (int it = 0; it < 4; ++it) {
            int e = it * 256 + tid;           // entry 0..1023
            int fi = e >> 6, l = e & 63;
            short8 o;
            if (isV) {
                // V B-frag: V[ks2*16+8*(l>>5)+i][db*32+(l&31)]
                int db = fi >> 1, ks2 = fi & 1;
                int row = ks2 * 16 + (l >> 5) * 8, col = db * 32 + (l & 31);
                #pragma unroll
                for (int i = 0; i < 8; ++i) o[i] = (short)f2bf(st[row + i][col]);
            } else {
                // K A-frag: K[(l&31)][ks*16+8*(l>>5)+i]
                int ks = fi;
                int row = l & 31, col = ks * 16 + (l >> 5) * 8;
                #pragma unroll
                for (int i = 0; i < 8; ++i) o[i] = (short)f2bf(st[row][col + i]);
            }
            *(short8*)(ob + e * 16) = o;
        }
    } else {
        // W slice (m, db): 16 rows x 256 cols -> swizzled bf16, chunk order (db*4+m)
        const int t = bid - 1024, m = t >> 4, db = t & 15;
        const float* wsrc = (m == 0 ? w0 : m == 1 ? w1 : m == 2 ? w2 : w3)
                            + (size_t)(db * 16) * D_;
        char* ob = ws + WBF_OFF + (size_t)(db * 4 + m) * 8192;
        #pragma unroll
        for (int it = 0; it < 2; ++it) {
            int gi = tid + it * 256;
            int r = gi >> 5, cg = gi & 31;
            float4 x0 = *(const float4*)(wsrc + (size_t)r * D_ + cg * 8);
            float4 x1 = *(const float4*)(wsrc + (size_t)r * D_ + cg * 8 + 4);
            *(short8*)(ob + r * 512 + ((cg * 16) ^ ((r & 7) << 4))) = pack8(x0, x1);
        }
    }
}

// ---------------------------------------------------------------- attn ----
union PaU { u32 w[4]; short8 s; };

__global__ __launch_bounds__(512, 1)
void attn_kernel(const float* __restrict__ q, const char* __restrict__ kimg,
                 const char* __restrict__ vimg, const char* __restrict__ wbf,
                 const float* __restrict__ v,
                 const float* __restrict__ bo0, const float* __restrict__ bo1,
                 float* __restrict__ out)
{
    __shared__ char smem[133632];

    const int tid = (int)threadIdx.x;
    const int wv = tid >> 6, lane = tid & 63;
    const int qh = wv >> 2, dh = wv & 3;
    const int h = lane >> 5, ln = lane & 31;
    const int g = lane >> 4 & 3, c = lane & 15;   // gate-phase decomposition
    const int bid = (int)blockIdx.x;
    const int b = bid & 7, qi = bid >> 3;
    const int q0 = qi * 64;
    const int qb = qi * 2 + qh;            // this wave's 32-row q block index
    const int qg = q0 + qh * 32 + ln;      // lane's q (lane axis of C)

    const char* kbaseg = kimg + ((size_t)b << 20);
    const char* vbaseg = vimg + ((size_t)b << 20);

    // Q B-frags for k quarter [dh*64, dh*64+64): element k = (dh*4+s)*16 + h*8 + i
    short8 qf[4];
    {
        const float* qp = q + ((size_t)b * S_ + (size_t)qg) * D_ + h * 8;
        #pragma unroll
        for (int s = 0; s < 4; ++s) {
            float4 a = *(const float4*)(qp + (dh * 4 + s) * 16);
            float4 d = *(const float4*)(qp + (dh * 4 + s) * 16 + 4);
            a.x *= QSCALE; a.y *= QSCALE; a.z *= QSCALE; a.w *= QSCALE;
            d.x *= QSCALE; d.y *= QSCALE; d.z *= QSCALE; d.w *= QSCALE;
            qf[s] = pack8(a, d);
        }
    }

    f32x16 accF[2] = {}, accB[2] = {};
    float sF = 0.0f, sB = 0.0f;

    #define STAGE_KV(t, buf)                                                   \
        {                                                                      \
            const char* kg_ = kbaseg + (size_t)(t) * 16384;                    \
            const char* vg_ = vbaseg + (size_t)(t) * 16384;                    \
            _Pragma("unroll")                                                  \
            for (int i = 0; i < 2; ++i) {                                      \
                int off = i * 8192 + wv * 1024 + lane * 16;                    \
                gload_lds(kg_ + off, smem + (buf) * 16384 + off);              \
                gload_lds(vg_ + off, smem + 32768 + (buf) * 16384 + off);      \
            }                                                                  \
        }

    STAGE_KV(0, 0);
    __syncthreads();

    // PV for this wave's d-quarter: frags at dh*4096 + db2*2048 + ks2*1024
    #define PVQ(pa0_, pa1_, accA_)                                             \
        {                                                                      \
            __builtin_amdgcn_s_setprio(1);                                     \
            short8 v0_ = *(const short8*)(vc);                                 \
            short8 v1_ = *(const short8*)(vc + 1024);                          \
            accA_[0] = mfma32(pa0_, v0_, accA_[0]);                            \
            accA_[0] = mfma32(pa1_, v1_, accA_[0]);                            \
            short8 v2_ = *(const short8*)(vc + 2048);                          \
            short8 v3_ = *(const short8*)(vc + 3072);                          \
            accA_[1] = mfma32(pa0_, v2_, accA_[1]);                            \
            accA_[1] = mfma32(pa1_, v3_, accA_[1]);                            \
            __builtin_amdgcn_s_setprio(0);                                     \
        }

    #define REPACK8(pa0_, pa1_, w0_, w1_, w2_, w3_, w4_, w5_, w6_, w7_)        \
        {                                                                      \
            plswap(w0_, w2_); plswap(w1_, w3_);                                \
            plswap(w4_, w6_); plswap(w5_, w7_);                                \
            PaU u0_; u0_.w[0] = w0_; u0_.w[1] = w1_; u0_.w[2] = w2_; u0_.w[3] = w3_; \
            PaU u1_; u1_.w[0] = w4_; u1_.w[1] = w5_; u1_.w[2] = w6_; u1_.w[3] = w7_; \
            pa0_ = u0_.s; pa1_ = u1_.s;                                        \
        }

    // masked score (diag): j = t*32 + (r&3)+8*(r>>2)+4h vs q = qg
    #define MEr(r_, CMP) (((jb32 + ((r_ & 3) + 8 * (r_ >> 2))) CMP qg) ? sc[r_] : 0.0f)

    #pragma unroll 1
    for (int t = 0; t < NP2; ++t) {
        const int cur = t & 1;
        if (t + 1 < NP2) STAGE_KV(t + 1, cur ^ 1);

        // ---- QK quarter: 4 MFMA over k in [dh*64, dh*64+64)
        const char* kc = smem + cur * 16384 + dh * 4096 + lane * 16;
        f32x16 sc = {};
        __builtin_amdgcn_s_setprio(1);
        #pragma unroll
        for (int s = 0; s < 4; ++s) {
            short8 kb = *(const short8*)(kc + s * 1024);
            sc = mfma32(kb, qf[s], sc);
        }
        __builtin_amdgcn_s_setprio(0);

        // ---- exchange partials: write own, raw barrier (lgkm only), read+sum partners
        {
            char* ex = smem + EXCH + (size_t)wv * 5120 + (size_t)lane * 80;
            f32x4 t0 = {sc[0], sc[1], sc[2], sc[3]};
            f32x4 t1 = {sc[4], sc[5], sc[6], sc[7]};
            f32x4 t2 = {sc[8], sc[9], sc[10], sc[11]};
            f32x4 t3 = {sc[12], sc[13], sc[14], sc[15]};
            *(f32x4*)(ex) = t0; *(f32x4*)(ex + 16) = t1;
            *(f32x4*)(ex + 32) = t2; *(f32x4*)(ex + 48) = t3;
        }
        asm volatile("" ::: "memory");
        asm volatile("s_waitcnt lgkmcnt(0)" ::: "memory");
        __builtin_amdgcn_s_barrier();
        asm volatile("" ::: "memory");
        #pragma unroll
        for (int p = 1; p < 4; ++p) {
            const char* px = smem + EXCH + (size_t)((qh << 2) | ((dh + p) & 3)) * 5120
                           + (size_t)lane * 80;
            f32x4 r0 = *(const f32x4*)(px);
            f32x4 r1 = *(const f32x4*)(px + 16);
            f32x4 r2 = *(const f32x4*)(px + 32);
            f32x4 r3 = *(const f32x4*)(px + 48);
            #pragma unroll
            for (int i = 0; i < 4; ++i) {
                sc[i] += r0[i]; sc[4 + i] += r1[i];
                sc[8 + i] += r2[i]; sc[12 + i] += r3[i];
            }
        }

        // ---- softmax numerator (no max; inputs bounded) + repack + PV
        #pragma unroll
        for (int i = 0; i < 16; ++i) sc[i] = exp2f(sc[i]);

        const char* vc = smem + 32768 + cur * 16384 + dh * 4096 + lane * 16;

        if (t != qb) {
            u32 w0 = pk2(sc[0], sc[1]),   w1 = pk2(sc[2], sc[3]);
            u32 w2 = pk2(sc[4], sc[5]),   w3 = pk2(sc[6], sc[7]);
            u32 w4 = pk2(sc[8], sc[9]),   w5 = pk2(sc[10], sc[11]);
            u32 w6 = pk2(sc[12], sc[13]), w7 = pk2(sc[14], sc[15]);
            float ts = (((sc[0]+sc[1])+(sc[2]+sc[3]))+((sc[4]+sc[5])+(sc[6]+sc[7])))
                     + (((sc[8]+sc[9])+(sc[10]+sc[11]))+((sc[12]+sc[13])+(sc[14]+sc[15])));
            ts += __shfl_xor(ts, 32);
            short8 pa0, pa1;
            REPACK8(pa0, pa1, w0, w1, w2, w3, w4, w5, w6, w7);
            if (t < qb) { sB += ts; PVQ(pa0, pa1, accB); }
            else        { sF += ts; PVQ(pa0, pa1, accF); }
        } else {
            const int jb32 = t * 32 + 4 * h;
            {   // bw: j <= q
                u32 w0 = pk2(MEr(0,<=), MEr(1,<=)),   w1 = pk2(MEr(2,<=), MEr(3,<=));
                u32 w2 = pk2(MEr(4,<=), MEr(5,<=)),   w3 = pk2(MEr(6,<=), MEr(7,<=));
                u32 w4 = pk2(MEr(8,<=), MEr(9,<=)),   w5 = pk2(MEr(10,<=), MEr(11,<=));
                u32 w6 = pk2(MEr(12,<=), MEr(13,<=)), w7 = pk2(MEr(14,<=), MEr(15,<=));
                float ts = 0.0f;
                #pragma unroll
                for (int r = 0; r < 16; ++r) ts += MEr(r, <=);
                ts += __shfl_xor(ts, 32);
                short8 pa0, pa1;
                REPACK8(pa0, pa1, w0, w1, w2, w3, w4, w5, w6, w7);
                sB += ts;
                PVQ(pa0, pa1, accB);
            }
            {   // fw: j >= q
                u32 w0 = pk2(MEr(0,>=), MEr(1,>=)),   w1 = pk2(MEr(2,>=), MEr(3,>=));
                u32 w2 = pk2(MEr(4,>=), MEr(5,>=)),   w3 = pk2(MEr(6,>=), MEr(7,>=));
                u32 w4 = pk2(MEr(8,>=), MEr(9,>=)),   w5 = pk2(MEr(10,>=), MEr(11,>=));
                u32 w6 = pk2(MEr(12,>=), MEr(13,>=)), w7 = pk2(MEr(14,>=), MEr(15,>=));
                float ts = 0.0f;
                #pragma unroll
                for (int r = 0; r < 16; ++r) ts += MEr(r, >=);
                ts += __shfl_xor(ts, 32);
                short8 pa0, pa1;
                REPACK8(pa0, pa1, w0, w1, w2, w3, w4, w5, w6, w7);
                sF += ts;
                PVQ(pa0, pa1, accF);
            }
        }
        __syncthreads();
    }

    // ---- epilogue (no F/B merge needed: every wave saw every j-block) ----
    // reciprocals of row sums (duplicated across dh and h; one writer)
    if (dh == 0 && h == 0) {
        float* sm = (float*)(smem + SUMS);
        sm[qh * 32 + ln] = 1.0f / sF;
        sm[64 + qh * 32 + ln] = 1.0f / sB;
    }
    __syncthreads();

    // normalize + write att images (F @[0,32K), B @[32K,64K)) + stage W chunk 0
    {
        const float* sm = (const float*)(smem + SUMS);
        #pragma unroll
        for (int db2 = 0; db2 < 2; ++db2)
            #pragma unroll
            for (int r = 0; r < 16; ++r) {
                int q32 = (r & 3) + 8 * (r >> 2) + 4 * h;
                int row = qh * 32 + q32;
                int dcol = dh * 64 + db2 * 32 + ln;
                int boff = row * 512 + ((2 * dcol) ^ ((row & 7) << 4));
                float mF = accF[db2][r] * sm[qh * 32 + q32];
                float mB = accB[db2][r] * sm[64 + qh * 32 + q32];
                *(u16*)(smem + boff) = f2bf(mF);
                *(u16*)(smem + 32768 + boff) = f2bf(mB);
            }
    }
    #define WSTAGE(db, buf)                                                    \
        {                                                                      \
            const char* gsrc = wbf + (size_t)(db) * 32768;                     \
            _Pragma("unroll")                                                  \
            for (int i = 0; i < 4; ++i) {                                      \
                int off = i * 8192 + wv * 1024;                                \
                gload_lds(gsrc + off + lane * 16,                              \
                          smem + 65536 + (buf) * 32768 + off);                 \
            }                                                                  \
        }
    WSTAGE(0, 0);
    __syncthreads();

    // gate phase: dir = dh&1, row group wl2 = qh*2 + (dh>>1) (16 rows each)
    const int dirg = dh & 1;
    const int wl2 = qh * 2 + (dh >> 1);
    const int swz = (c & 7) << 4;
    short8 af[8], vf[8];
    {
        const char* imgb = smem + dirg * 32768;
        int lr = wl2 * 16 + c;
        #pragma unroll
        for (int ks = 0; ks < 8; ++ks) {
            int inner = (ks * 64 + g * 16) ^ ((lr & 7) << 4);
            af[ks] = *(const short8*)(imgb + lr * 512 + inner);
        }
        const float* vp = v + ((size_t)b * S_ + (size_t)(q0 + wl2 * 16 + c)) * D_;
        #pragma unroll
        for (int ks = 0; ks < 8; ++ks) {
            float4 a = *(const float4*)(vp + ks * 32 + g * 8);
            float4 d = *(const float4*)(vp + ks * 32 + g * 8 + 4);
            vf[ks] = pack8(a, d);
        }
    }

    const float* bias = dirg ? bo1 : bo0;
    const float* vrow = v + ((size_t)b * S_ + (size_t)(q0 + wl2 * 16)) * D_;
    const char* imgb2 = smem + dirg * 32768;
    float* ob = out + ((size_t)b * S_ + (size_t)(q0 + wl2 * 16)) * 512 + dirg * 256;
    #pragma unroll
    for (int db = 0; db < 16; ++db) {
        const int cu2 = db & 1;
        if (db + 1 < 16) WSTAGE(db + 1, cu2 ^ 1);

        float bb = bias[db * 16 + c];
        f32x4 a = {bb, bb, bb, bb};
        const char* wc = smem + 65536 + cu2 * 32768 + dirg * 16384;
        __builtin_amdgcn_s_setprio(1);
        #pragma unroll
        for (int ks = 0; ks < 8; ++ks) {
            int inner = (ks * 64 + g * 16) ^ swz;
            short8 wi = *(const short8*)(wc + c * 512 + inner);
            short8 wo = *(const short8*)(wc + 8192 + c * 512 + inner);
            a = mfma16(vf[ks], wi, a);
            a = mfma16(af[ks], wo, a);
        }
        __builtin_amdgcn_s_setprio(0);

        #pragma unroll
        for (int r = 0; r < 4; ++r) {
            int row = wl2 * 16 + g * 4 + r;
            int cc = db * 16 + c;
            float vv = vrow[(size_t)(g * 4 + r) * D_ + cc];
            u32 mu = *(const u16*)(imgb2 + row * 512 + ((2 * cc) ^ ((row & 7) << 4)));
            union { u32 u; float f; } cv; cv.u = mu << 16;
            float gate = 1.0f / (1.0f + exp2f(-a[r] * LOG2E));
            ob[(size_t)(g * 4 + r) * 512 + cc] = gate * cv.f + (1.0f - gate) * vv;
        }
        __syncthreads();
    }
}

extern "C" void kernel_launch(void* const* d_in, const int* in_sizes, int n_in,
                              void* d_out, int out_size, void* d_ws, size_t ws_size,
                              hipStream_t stream)
{
    const float* q   = (const float*)d_in[0];
    const float* k   = (const float*)d_in[1];
    const float* v   = (const float*)d_in[2];
    const float* Wi0 = (const float*)d_in[3];
    const float* Wi1 = (const float*)d_in[4];
    const float* Wo0 = (const float*)d_in[5];
    const float* Wo1 = (const float*)d_in[6];
    const float* bo0 = (const float*)d_in[7];
    const float* bo1 = (const float*)d_in[8];
    float* out = (float*)d_out;
    char* ws = (char*)d_ws;
    (void)in_sizes; (void)n_in; (void)ws_size; (void)out_size;

    prep_kernel<<<dim3(1088), dim3(256), 0, stream>>>(k, v, Wi0, Wo0, Wi1, Wo1, ws);
    attn_kernel<<<dim3(256), dim3(512), 0, stream>>>(q, ws + KIMG_OFF, ws + VIMG_OFF,
                                                     ws + WBF_OFF, v, bo0, bo1, out);
}